// Round 1
// 379.136 us; speedup vs baseline: 1.0043x; 1.0043x over previous
//
#include <hip/hip_runtime.h>
#include <math.h>

#define DFEAT 4096
#define NQ 6
#define ROWS_PER_WAVE 4
#define WAVES_PER_BLOCK 4
#define ROWS_PER_BLOCK (ROWS_PER_WAVE * WAVES_PER_BLOCK)
#define SLAB 256                 // k-elements per wave-iteration (64 lanes x float4)
#define NIT (DFEAT / SLAB)       // 16

typedef float floatx4 __attribute__((ext_vector_type(4)));

// Nontemporal load: x is a 268 MB zero-reuse stream; bypass L2 allocation so
// the per-XCD 4 MiB L2 keeps the W1 slab (98 KB, reused 16x/CU) resident
// instead of thrashing on stream data. W1/b1/qw/W2 stay on the cached path.
__device__ __forceinline__ floatx4 ldnt(const float* p) {
    return __builtin_nontemporal_load(reinterpret_cast<const floatx4*>(p));
}

// Fused: h = x@W1 + b1; a = h/||h||; 15 RBS (Givens) rotations; z = 1-2a^2
// (NaN->0); out = sigmoid(z@W2 + b2).
//
// R5 structure kept: no LDS, both x and W1 software-pipelined 2 deep with
// 2-buffer rotation (loads for it+2 issued as buffer (it&1) is consumed;
// ~8 KB x in flight per wave, ~128 KB/CU). No barriers anywhere.
// __launch_bounds__(256,4) caps VGPR at 128 -> 16 waves/CU resident.
// R6: x loads are nontemporal (see ldnt above).
__global__ __launch_bounds__(256, 4)
void hybrid_fused_kernel(const float* __restrict__ x,
                         const float* __restrict__ W1,
                         const float* __restrict__ b1,
                         const float* __restrict__ qw,
                         const float* __restrict__ W2,
                         const float* __restrict__ b2,
                         float* __restrict__ out, int B)
{
    const int t = threadIdx.x;
    const int lane = t & 63;
    const int wave = t >> 6;
    const int row0 = (blockIdx.x * WAVES_PER_BLOCK + wave) * ROWS_PER_WAVE;
    if (row0 >= B) return;

    const float* xp[ROWS_PER_WAVE];
#pragma unroll
    for (int r = 0; r < ROWS_PER_WAVE; ++r) {
        int rr = row0 + r; if (rr > B - 1) rr = B - 1;
        xp[r] = x + (size_t)rr * DFEAT;
    }
    // W1 fragment base for this lane: rows (it*256 + lane*4)..+3, 6 cols each
    // = 24 contiguous floats = 6 float4s (96 B, 16B-aligned).
    const floatx4* wfrag0 =
        reinterpret_cast<const floatx4*>(W1 + (size_t)lane * 4 * NQ);

    float acc[ROWS_PER_WAVE][NQ];
#pragma unroll
    for (int r = 0; r < ROWS_PER_WAVE; ++r)
#pragma unroll
        for (int j = 0; j < NQ; ++j) acc[r][j] = 0.0f;

    // Double-buffered pipeline registers: x (4 rows x float4) and W1 (6 float4).
    floatx4 xb[2][ROWS_PER_WAVE];
    floatx4 wb[2][NQ];

    // Prologue: fill both buffers (iterations 0 and 1).
#pragma unroll
    for (int p = 0; p < 2; ++p) {
        const int d = p * SLAB + lane * 4;
#pragma unroll
        for (int r = 0; r < ROWS_PER_WAVE; ++r)
            xb[p][r] = ldnt(xp[r] + d);
        const floatx4* wf = wfrag0 + (size_t)p * SLAB * NQ / 4;
#pragma unroll
        for (int j = 0; j < NQ; ++j)
            wb[p][j] = wf[j];
    }

    for (int it = 0; it < NIT; ++it) {
        const int cur = it & 1;

        // Consume buffer `cur` (loads were issued 2 iterations ago).
        // wb[cur][j] holds W1 rows d..d+3 in row-major 4x6; transpose inline:
        // w[k][j] = wb[cur][(4k+j)/4][(4k+j)%4]  -- done via component refs.
        const floatx4 w0 = wb[cur][0], w1 = wb[cur][1], w2 = wb[cur][2];
        const floatx4 w3 = wb[cur][3], w4 = wb[cur][4], w5 = wb[cur][5];
        // Row k of W1 fragment (6 floats each):
        // k=0: w0.x w0.y w0.z w0.w w1.x w1.y
        // k=1: w1.z w1.w w2.x w2.y w2.z w2.w
        // k=2: w3.x w3.y w3.z w3.w w4.x w4.y
        // k=3: w4.z w4.w w5.x w5.y w5.z w5.w
#pragma unroll
        for (int r = 0; r < ROWS_PER_WAVE; ++r) {
            const floatx4 xv = xb[cur][r];
            float* A = acc[r];
            A[0] = fmaf(xv.x, w0.x, A[0]); A[1] = fmaf(xv.x, w0.y, A[1]);
            A[2] = fmaf(xv.x, w0.z, A[2]); A[3] = fmaf(xv.x, w0.w, A[3]);
            A[4] = fmaf(xv.x, w1.x, A[4]); A[5] = fmaf(xv.x, w1.y, A[5]);

            A[0] = fmaf(xv.y, w1.z, A[0]); A[1] = fmaf(xv.y, w1.w, A[1]);
            A[2] = fmaf(xv.y, w2.x, A[2]); A[3] = fmaf(xv.y, w2.y, A[3]);
            A[4] = fmaf(xv.y, w2.z, A[4]); A[5] = fmaf(xv.y, w2.w, A[5]);

            A[0] = fmaf(xv.z, w3.x, A[0]); A[1] = fmaf(xv.z, w3.y, A[1]);
            A[2] = fmaf(xv.z, w3.z, A[2]); A[3] = fmaf(xv.z, w3.w, A[3]);
            A[4] = fmaf(xv.z, w4.x, A[4]); A[5] = fmaf(xv.z, w4.y, A[5]);

            A[0] = fmaf(xv.w, w4.z, A[0]); A[1] = fmaf(xv.w, w4.w, A[1]);
            A[2] = fmaf(xv.w, w5.x, A[2]); A[3] = fmaf(xv.w, w5.y, A[3]);
            A[4] = fmaf(xv.w, w5.z, A[4]); A[5] = fmaf(xv.w, w5.w, A[5]);
        }

        // Refill buffer `cur` for iteration it+2 (in flight across it+1).
        if (it + 2 < NIT) {
            const int d = (it + 2) * SLAB + lane * 4;
#pragma unroll
            for (int r = 0; r < ROWS_PER_WAVE; ++r)
                xb[cur][r] = ldnt(xp[r] + d);
            const floatx4* wf = wfrag0 + (size_t)(it + 2) * SLAB * NQ / 4;
#pragma unroll
            for (int j = 0; j < NQ; ++j)
                wb[cur][j] = wf[j];
        }
    }

    // Wave-wide butterfly reduction: every lane ends with the full sums.
#pragma unroll
    for (int r = 0; r < ROWS_PER_WAVE; ++r)
#pragma unroll
        for (int j = 0; j < NQ; ++j) {
            float v = acc[r][j];
#pragma unroll
            for (int offs = 32; offs >= 1; offs >>= 1)
                v += __shfl_xor(v, offs, 64);
            acc[r][j] = v;
        }

    // Tail: lanes 0..3 each finish one row.
    if (lane < ROWS_PER_WAVE) {
        float h[NQ];
#pragma unroll
        for (int j = 0; j < NQ; ++j) {
            float v = acc[0][j];
            v = (lane == 1) ? acc[1][j] : v;
            v = (lane == 2) ? acc[2][j] : v;
            v = (lane == 3) ? acc[3][j] : v;
            h[j] = v + b1[j];
        }
        float n2 = 0.0f;
#pragma unroll
        for (int j = 0; j < NQ; ++j) n2 = fmaf(h[j], h[j], n2);
        const float inv = rsqrtf(n2);
        float a[NQ];
#pragma unroll
        for (int j = 0; j < NQ; ++j) a[j] = h[j] * inv;

        // pyramid_top_wires(6) = [4,3,2,4,1,3,0,2,4,1,3,2,4,3,4]
        const int topw[15] = {4,3,2,4,1,3,0,2,4,1,3,2,4,3,4};
#pragma unroll
        for (int k = 0; k < 15; ++k) {
            const int q = topw[k];          // constant after unroll
            const float c = cosf(qw[k]);
            const float s = sinf(qw[k]);
            const float aq  = fmaf(c, a[q],     s * a[q + 1]);
            const float aq1 = fmaf(c, a[q + 1], -s * a[q]);
            a[q] = aq;
            a[q + 1] = aq1;
        }

        float zac = b2[0];
#pragma unroll
        for (int j = 0; j < NQ; ++j) {
            float z = 1.0f - 2.0f * a[j] * a[j];
            z = isnan(z) ? 0.0f : z;        // NaN guard from reference
            zac = fmaf(z, W2[j], zac);
        }
        const float o = 1.0f / (1.0f + expf(-zac));
        const int row = row0 + lane;
        if (row < B) out[row] = o;
    }
}

extern "C" void kernel_launch(void* const* d_in, const int* in_sizes, int n_in,
                              void* d_out, int out_size, void* d_ws, size_t ws_size,
                              hipStream_t stream) {
    const float* x  = (const float*)d_in[0];
    const float* W1 = (const float*)d_in[1];
    const float* b1 = (const float*)d_in[2];
    const float* qw = (const float*)d_in[3];
    const float* W2 = (const float*)d_in[4];
    const float* b2 = (const float*)d_in[5];
    float* out = (float*)d_out;

    const int B = in_sizes[0] / DFEAT;                             // 16384
    const int blocks = (B + ROWS_PER_BLOCK - 1) / ROWS_PER_BLOCK;  // 1024
    hybrid_fused_kernel<<<blocks, 256, 0, stream>>>(x, W1, b1, qw, W2, b2, out, B);
}